// Round 4
// baseline (826.594 us; speedup 1.0000x reference)
//
#include <hip/hip_runtime.h>
#include <hip/hip_bf16.h>
#include <cfloat>

// Problem constants (GeoTokenizer): B=8, N=4096 -> M=32768 rows
#define M_ROWS 32768
#define DIM    768
#define VOCABN 4096
#define HIDN   128
#define QT     32      // (fallback) queries per block in old argmin
#define QB     64      // (fallback) queries per argmin block
#define CAP    32      // (fallback) candidate buffer per query
#define MARGIN 2.0f    // 2*delta; |approx-exact| bound delta=1.0 (validated R2/R3)

// Phase-1 GEMM tiling
#define BM 128
#define BN 128
#define NCB (VOCABN / BN)   // 32 code-blocks
#define CAP2 6              // stored candidates per (query, code-block)

typedef __attribute__((ext_vector_type(8))) short bf16x8;  // MFMA A/B frag
typedef __attribute__((ext_vector_type(4))) float f32x4;   // MFMA C/D frag

static __device__ __forceinline__ short f2b(float x) {
    __hip_bfloat16 h = __float2bfloat16(x);   // RNE
    return *reinterpret_cast<short*>(&h);
}

// async global->LDS, 16B per lane; LDS dest = wave-uniform base + lane*16
static __device__ __forceinline__ void gld_lds16(const void* g, void* lds) {
    __builtin_amdgcn_global_load_lds(
        (const __attribute__((address_space(1))) void*)g,
        (__attribute__((address_space(3))) void*)lds,
        16, 0, 0);
}

// ---------------------------------------------------------------------------
// Kernel 1: fused two-branch MLP encoder (fp32 exact). 32 rows/block.
// ---------------------------------------------------------------------------
__global__ __launch_bounds__(256) void encode_kernel(
    const float* __restrict__ coords, const float* __restrict__ feats,
    const float* __restrict__ Ws1, const float* __restrict__ bs1,
    const float* __restrict__ Ws2, const float* __restrict__ bs2,
    const float* __restrict__ Wf1, const float* __restrict__ bf1,
    const float* __restrict__ Wf2, const float* __restrict__ bf2,
    float* __restrict__ comb, short* __restrict__ comb16, int write16)
{
    __shared__ float hs[32][HIDN];
    __shared__ float hf[32][HIDN];
    const int row0 = blockIdx.x * 32;
    const int t = threadIdx.x;

    #pragma unroll
    for (int k = 0; k < 16; ++k) {
        const int idx = t + k * 256;
        const int r = idx >> 7;
        const int j = idx & 127;
        const int row = row0 + r;
        const float c0 = coords[row * 2 + 0];
        const float c1 = coords[row * 2 + 1];
        float vs = fmaf(c0, Ws1[j], fmaf(c1, Ws1[HIDN + j], bs1[j]));
        hs[r][j] = fmaxf(vs, 0.0f);
        float vf = bf1[j];
        #pragma unroll
        for (int i = 0; i < 10; ++i)
            vf = fmaf(feats[row * 10 + i], Wf1[i * HIDN + j], vf);
        hf[r][j] = fmaxf(vf, 0.0f);
    }
    __syncthreads();

    float acc[3][32];
    #pragma unroll
    for (int dd = 0; dd < 3; ++dd) {
        const float base = bs2[t + dd * 256] + bf2[t + dd * 256];
        #pragma unroll
        for (int r = 0; r < 32; ++r) acc[dd][r] = base;
    }

    for (int jq = 0; jq < 32; ++jq) {
        float ws[3][4], wf[3][4];
        #pragma unroll
        for (int dd = 0; dd < 3; ++dd) {
            const int d = t + dd * 256;
            #pragma unroll
            for (int jj = 0; jj < 4; ++jj) {
                ws[dd][jj] = Ws2[(jq * 4 + jj) * DIM + d];
                wf[dd][jj] = Wf2[(jq * 4 + jj) * DIM + d];
            }
        }
        #pragma unroll
        for (int r = 0; r < 32; ++r) {
            const float4 h4s = *(const float4*)&hs[r][jq * 4];
            const float4 h4f = *(const float4*)&hf[r][jq * 4];
            #pragma unroll
            for (int dd = 0; dd < 3; ++dd) {
                float a = acc[dd][r];
                a = fmaf(h4s.x, ws[dd][0], a);
                a = fmaf(h4s.y, ws[dd][1], a);
                a = fmaf(h4s.z, ws[dd][2], a);
                a = fmaf(h4s.w, ws[dd][3], a);
                a = fmaf(h4f.x, wf[dd][0], a);
                a = fmaf(h4f.y, wf[dd][1], a);
                a = fmaf(h4f.z, wf[dd][2], a);
                a = fmaf(h4f.w, wf[dd][3], a);
                acc[dd][r] = a;
            }
        }
    }

    #pragma unroll
    for (int dd = 0; dd < 3; ++dd) {
        const int d = t + dd * 256;
        #pragma unroll
        for (int r = 0; r < 32; ++r) {
            const float v = acc[dd][r];
            comb[(size_t)(row0 + r) * DIM + d] = v;
            if (write16) comb16[(size_t)(row0 + r) * DIM + d] = f2b(v);
        }
    }
}

// ---------------------------------------------------------------------------
// Kernel 2: c_sq[v] = ||codebook[v]||^2 (fp32) + bf16 codebook conversion.
// ---------------------------------------------------------------------------
__global__ __launch_bounds__(64) void csq_cvt_kernel(
    const float* __restrict__ codebook, float* __restrict__ csq,
    __hip_bfloat16* __restrict__ cbb)
{
    const int v = blockIdx.x;
    const int l = threadIdx.x;
    float s = 0.0f;
    #pragma unroll
    for (int k = 0; k < DIM / 64; ++k) {
        const float x = codebook[(size_t)v * DIM + l + k * 64];
        cbb[(size_t)v * DIM + l + k * 64] = __float2bfloat16(x);
        s = fmaf(x, x, s);
    }
    #pragma unroll
    for (int off = 32; off >= 1; off >>= 1)
        s += __shfl_down(s, off);
    if (l == 0) csq[v] = s;
}

// ---------------------------------------------------------------------------
// Kernel 3 (phase 1): 128x128 bf16 MFMA GEMM over K=768 with fused
// per-(query, code-block) local min/argmin + margin-candidate extraction.
// R4 change: ALL aux outputs are [cb][q] so stores are fully coalesced
// (R3 had [q][cb] -> 128B-strided 4B stores -> 164MB write amp + RFO fetch).
// ---------------------------------------------------------------------------
__global__ __launch_bounds__(256) void vq_phase1_kernel(
    const short* __restrict__ comb16, const short* __restrict__ cbb,
    const float* __restrict__ csq,
    float* __restrict__ lmin_g, int* __restrict__ lbidx_g,
    int* __restrict__ lcnt_g, int* __restrict__ lci_g, float* __restrict__ lcd_g)
{
    __shared__ short sA[BM * 64];          // 16 KB
    __shared__ short sB[BN * 64];          // 16 KB
    __shared__ float s_wmin[2][BM];
    __shared__ int   s_widx[2][BM];
    __shared__ float s_thr[BM];
    __shared__ int   s_cnt[BM];
    __shared__ int   s_ci[BM][CAP2];
    __shared__ float s_cd[BM][CAP2];

    const int t = threadIdx.x;
    const int w = t >> 6, l = t & 63;
    const int lm = l & 15, quad = l >> 4;
    const int wr = w & 1, wc = w >> 1;
    const int cb = blockIdx.x;             // 0..31
    const int q0 = blockIdx.y * BM;

    if (t < BM) s_cnt[t] = 0;

    // ---- staging addresses (wave w stages rows [w*32, w*32+32) of A and B)
    const int rsub  = l >> 3;              // 0..7
    const int kslot = l & 7;               // physical 16B slot within row
    const int kk    = kslot ^ rsub;        // logical k-group (XOR swizzle)
    const short* gA[4];
    const short* gB[4];
    int ldsOff[4];
    #pragma unroll
    for (int i = 0; i < 4; ++i) {
        const int row = w * 32 + i * 8 + rsub;
        gA[i] = comb16 + (size_t)(q0 + row) * DIM + kk * 8;
        gB[i] = cbb    + (size_t)(cb * BN + row) * DIM + kk * 8;
        ldsOff[i] = (w * 32 + i * 8) * 64;  // wave-uniform (shorts)
    }

    // ---- fragment LDS offsets (constant across K-iters; swizzle-matched)
    int aOff[4][2], bOff[4][2];
    #pragma unroll
    for (int i = 0; i < 4; ++i)
        #pragma unroll
        for (int s = 0; s < 2; ++s) {
            const int x = ((s << 2) | quad) ^ (lm & 7);
            aOff[i][s] = (wr * 64 + i * 16 + lm) * 64 + x * 8;
            bOff[i][s] = (wc * 64 + i * 16 + lm) * 64 + x * 8;
        }

    f32x4 acc[4][4];
    #pragma unroll
    for (int i = 0; i < 4; ++i)
        #pragma unroll
        for (int j = 0; j < 4; ++j) acc[i][j] = (f32x4){0.f, 0.f, 0.f, 0.f};

    // ---- K loop: 12 iters of BK=64 (2 MFMA k-steps each)
    for (int kt = 0; kt < 12; ++kt) {
        __syncthreads();
        #pragma unroll
        for (int i = 0; i < 4; ++i) {
            gld_lds16(gA[i] + kt * 64, &sA[ldsOff[i]]);
            gld_lds16(gB[i] + kt * 64, &sB[ldsOff[i]]);
        }
        __syncthreads();
        #pragma unroll
        for (int s = 0; s < 2; ++s) {
            bf16x8 a[4], b[4];
            #pragma unroll
            for (int i = 0; i < 4; ++i) a[i] = *(const bf16x8*)&sA[aOff[i][s]];
            #pragma unroll
            for (int j = 0; j < 4; ++j) b[j] = *(const bf16x8*)&sB[bOff[j][s]];
            #pragma unroll
            for (int i = 0; i < 4; ++i)
                #pragma unroll
                for (int j = 0; j < 4; ++j)
                    acc[i][j] = __builtin_amdgcn_mfma_f32_16x16x32_bf16(
                        a[i], b[j], acc[i][j], 0, 0, 0);
        }
    }

    // ---- epilogue: dist = csq - 2*dot (x_sq dropped, argmin-invariant)
    const int cbase = cb * BN + wc * 64;
    float cs[4];
    #pragma unroll
    for (int j = 0; j < 4; ++j) cs[j] = csq[cbase + j * 16 + lm];
    #pragma unroll
    for (int i = 0; i < 4; ++i)
        #pragma unroll
        for (int j = 0; j < 4; ++j)
            #pragma unroll
            for (int r = 0; r < 4; ++r)
                acc[i][j][r] = fmaf(-2.0f, acc[i][j][r], cs[j]);

    // per-query (i,r) min/argmin over j-tiles then over 16 lanes of the quad
    #pragma unroll
    for (int i = 0; i < 4; ++i)
        #pragma unroll
        for (int r = 0; r < 4; ++r) {
            float m = acc[i][0][r];
            int mi = cbase + 0 * 16 + lm;
            #pragma unroll
            for (int j = 1; j < 4; ++j) {
                const float d = acc[i][j][r];
                const int ci = cbase + j * 16 + lm;
                if (d < m || (d == m && ci < mi)) { m = d; mi = ci; }
            }
            #pragma unroll
            for (int off = 1; off <= 8; off <<= 1) {   // stays within quad
                const float om = __shfl_xor(m, off);
                const int oi = __shfl_xor(mi, off);
                if (om < m || (om == m && oi < mi)) { m = om; mi = oi; }
            }
            if (lm == 0) {
                const int qloc = wr * 64 + i * 16 + quad * 4 + r;
                s_wmin[wc][qloc] = m;
                s_widx[wc][qloc] = mi;
            }
        }
    __syncthreads();

    if (t < BM) {
        const float v0 = s_wmin[0][t], v1 = s_wmin[1][t];
        const int i0 = s_widx[0][t], i1 = s_widx[1][t];
        const float bm = fminf(v0, v1);
        const int bi = (v1 < v0 || (v1 == v0 && i1 < i0)) ? i1 : i0;
        const size_t base = (size_t)cb * M_ROWS + (q0 + t);   // [cb][q] coalesced
        lmin_g[base] = bm;
        lbidx_g[base] = bi;
        s_thr[t] = bm + MARGIN;
    }
    __syncthreads();

    // candidate pass: push everything within margin of the block-local min
    #pragma unroll
    for (int i = 0; i < 4; ++i)
        #pragma unroll
        for (int r = 0; r < 4; ++r) {
            const int qloc = wr * 64 + i * 16 + quad * 4 + r;
            const float thr = s_thr[qloc];
            #pragma unroll
            for (int j = 0; j < 4; ++j) {
                const float d = acc[i][j][r];
                if (d <= thr) {
                    const int p = atomicAdd(&s_cnt[qloc], 1);
                    if (p < CAP2) {
                        s_ci[qloc][p] = cbase + j * 16 + lm;
                        s_cd[qloc][p] = d;
                    }
                }
            }
        }
    __syncthreads();

    if (t < BM) {
        const size_t base = (size_t)cb * M_ROWS + (q0 + t);   // [cb][q] coalesced
        int n = s_cnt[t];
        if (n > CAP2) n = CAP2;
        lcnt_g[base] = n;
        for (int p = 0; p < n; ++p) {
            lci_g[base * CAP2 + p] = s_ci[t][p];
            lcd_g[base * CAP2 + p] = s_cd[t][p];
        }
    }
}

// ---------------------------------------------------------------------------
// Kernel 4 (phase 2): per query, G = min of 32 local mins; filter candidates
// to d <= G+MARGIN (~1-3 survive); exact fp32 re-rank; fused gather.
// Aux arrays are [cb][q] (transposed in R4).
// ---------------------------------------------------------------------------
__global__ __launch_bounds__(256) void vq_phase2_kernel(
    const float* __restrict__ comb32, const float* __restrict__ codebook,
    const float* __restrict__ csq,
    const float* __restrict__ lmin_g, const int* __restrict__ lbidx_g,
    const int* __restrict__ lcnt_g, const int* __restrict__ lci_g,
    const float* __restrict__ lcd_g,
    float* __restrict__ out_tok_f, float* __restrict__ out_q)
{
    __shared__ int s2n[4];
    __shared__ int s2c[4][32];
    const int t = threadIdx.x, w = t >> 6, l = t & 63;
    const int q = blockIdx.x * 4 + w;
    if (t < 4) s2n[t] = 0;
    __syncthreads();

    const size_t base = (size_t)l * M_ROWS + q;   // lane l = code-block l
    float lv = (l < NCB) ? lmin_g[base] : FLT_MAX;
    #pragma unroll
    for (int off = 1; off <= 32; off <<= 1)
        lv = fminf(lv, __shfl_xor(lv, off));
    const float thr = lv + MARGIN;

    if (l < NCB) {
        if (lmin_g[base] <= thr) {           // block-local argmin always safe
            const int p = atomicAdd(&s2n[w], 1);
            if (p < 32) s2c[w][p] = lbidx_g[base];
        }
        int n = lcnt_g[base];
        if (n > CAP2) n = CAP2;
        for (int p = 0; p < n; ++p) {
            if (lcd_g[base * CAP2 + p] <= thr) {
                const int pos = atomicAdd(&s2n[w], 1);
                if (pos < 32) s2c[w][pos] = lci_g[base * CAP2 + p];
            }
        }
    }
    __syncthreads();

    int ns = s2n[w];
    if (ns > 32) ns = 32;
    float bestd = FLT_MAX;
    int bestc = 0x7fffffff;
    const float4* xr = (const float4*)(comb32 + (size_t)q * DIM);
    for (int e = 0; e < ns; ++e) {
        const int c = s2c[w][e];
        const float4* cr = (const float4*)(codebook + (size_t)c * DIM);
        float dot = 0.0f;
        #pragma unroll
        for (int k = 0; k < 3; ++k) {
            const float4 x = xr[l + 64 * k];
            const float4 y = cr[l + 64 * k];
            dot = fmaf(x.x, y.x, fmaf(x.y, y.y, fmaf(x.z, y.z, fmaf(x.w, y.w, dot))));
        }
        #pragma unroll
        for (int off = 1; off <= 32; off <<= 1)
            dot += __shfl_xor(dot, off);     // bitwise-identical in all lanes
        const float d = fmaf(-2.0f, dot, csq[c]);
        if (d < bestd || (d == bestd && c < bestc)) { bestd = d; bestc = c; }
    }
    if (l == 0) out_tok_f[q] = (float)bestc;
    // fused gather (bestc identical across lanes)
    const float4* cr = (const float4*)(codebook + (size_t)bestc * DIM);
    float4* o4 = (float4*)(out_q + (size_t)q * DIM);
    #pragma unroll
    for (int k = 0; k < 3; ++k) o4[l + 64 * k] = cr[l + 64 * k];
}

// ===========================================================================
// FALLBACK PATH (R2, proven): used only if ws_size is too small for phase1/2.
// ===========================================================================
__global__ __launch_bounds__(256) void argmin_mfma_kernel(
    const float* __restrict__ comb, const float* __restrict__ codebook,
    const __hip_bfloat16* __restrict__ cbb, const float* __restrict__ csq,
    float* __restrict__ out_tok_f, int* __restrict__ tok_i)
{
    __shared__ int s_cnt[QB];
    __shared__ int s_cand[QB][CAP];

    const int t = threadIdx.x;
    const int w = t >> 6;
    const int l = t & 63;
    const int lm = l & 15;
    const int quad = l >> 4;
    const int q0 = blockIdx.x * QB;

    for (int i = t; i < QB; i += 256) s_cnt[i] = 0;
    __syncthreads();

    bf16x8 a_reg[24];
    {
        const int qa = q0 + w * 16 + lm;
        const float* ap = comb + (size_t)qa * DIM + quad * 8;
        #pragma unroll
        for (int kc = 0; kc < 24; ++kc) {
            const float4 lo = *(const float4*)(ap + kc * 32);
            const float4 hi = *(const float4*)(ap + kc * 32 + 4);
            bf16x8 f;
            f[0] = f2b(lo.x); f[1] = f2b(lo.y); f[2] = f2b(lo.z); f[3] = f2b(lo.w);
            f[4] = f2b(hi.x); f[5] = f2b(hi.y); f[6] = f2b(hi.z); f[7] = f2b(hi.w);
            a_reg[kc] = f;
        }
    }

    const short* cbbs = (const short*)cbb;
    const short* bp = cbbs + (size_t)lm * DIM + quad * 8;

    float runmin[4] = {FLT_MAX, FLT_MAX, FLT_MAX, FLT_MAX};

    for (int chunk = 0; chunk < VOCABN / 64; ++chunk) {
        const int c0 = chunk * 64;
        const short* bc = bp + (size_t)c0 * DIM;
        f32x4 acc[4];
        #pragma unroll
        for (int s = 0; s < 4; ++s) acc[s] = (f32x4){0.f, 0.f, 0.f, 0.f};

        #pragma unroll
        for (int kc = 0; kc < 24; ++kc) {
            const bf16x8 a = a_reg[kc];
            #pragma unroll
            for (int s = 0; s < 4; ++s) {
                const bf16x8 b = *(const bf16x8*)(bc + s * 16 * DIM + kc * 32);
                acc[s] = __builtin_amdgcn_mfma_f32_16x16x32_bf16(a, b, acc[s], 0, 0, 0);
            }
        }

        float d[4][4];
        float m[4] = {FLT_MAX, FLT_MAX, FLT_MAX, FLT_MAX};
        #pragma unroll
        for (int s = 0; s < 4; ++s) {
            const float csv = csq[c0 + s * 16 + lm];
            #pragma unroll
            for (int r = 0; r < 4; ++r) {
                d[s][r] = fmaf(-2.0f, acc[s][r], csv);
                m[r] = fminf(m[r], d[s][r]);
            }
        }
        #pragma unroll
        for (int r = 0; r < 4; ++r) {
            float v = m[r];
            v = fminf(v, __shfl_xor(v, 1));
            v = fminf(v, __shfl_xor(v, 2));
            v = fminf(v, __shfl_xor(v, 4));
            v = fminf(v, __shfl_xor(v, 8));
            runmin[r] = fminf(runmin[r], v);
        }
        #pragma unroll
        for (int s = 0; s < 4; ++s) {
            #pragma unroll
            for (int r = 0; r < 4; ++r) {
                if (d[s][r] <= runmin[r] + MARGIN) {
                    const int qloc = w * 16 + quad * 4 + r;
                    const int idx = atomicAdd(&s_cnt[qloc], 1);
                    if (idx < CAP) s_cand[qloc][idx] = c0 + s * 16 + lm;
                }
            }
        }
    }
    __syncthreads();

    const int qloc = t >> 2;
    const int sub = t & 3;
    const int qg = q0 + qloc;
    int n = s_cnt[qloc];
    if (n > CAP) n = CAP;
    float bestd = FLT_MAX;
    int bestc = 0x7fffffff;
    const float4* xr = (const float4*)(comb + (size_t)qg * DIM);
    for (int i = 0; i < n; ++i) {
        const int c = s_cand[qloc][i];
        const float4* cr = (const float4*)(codebook + (size_t)c * DIM);
        float dot = 0.0f;
        #pragma unroll 4
        for (int j = sub * 48; j < sub * 48 + 48; ++j) {
            const float4 x = xr[j];
            const float4 y = cr[j];
            dot = fmaf(x.x, y.x, fmaf(x.y, y.y, fmaf(x.z, y.z, fmaf(x.w, y.w, dot))));
        }
        dot += __shfl_xor(dot, 1);
        dot += __shfl_xor(dot, 2);
        const float dist = fmaf(-2.0f, dot, csq[c]);
        if (dist < bestd || (dist == bestd && c < bestc)) { bestd = dist; bestc = c; }
    }
    if (sub == 0) {
        out_tok_f[qg] = (float)bestc;
        tok_i[qg] = bestc;
    }
}

__global__ __launch_bounds__(192) void gather_kernel(
    const int* __restrict__ tok, const float* __restrict__ codebook,
    float* __restrict__ outq)
{
    const int row = blockIdx.x;
    const int t = threadIdx.x;
    const int token = tok[row];
    const float4* cb4 = (const float4*)(codebook + (size_t)token * DIM);
    float4* o4 = (float4*)(outq + (size_t)row * DIM);
    o4[t] = cb4[t];
}

// ===========================================================================
extern "C" void kernel_launch(void* const* d_in, const int* in_sizes, int n_in,
                              void* d_out, int out_size, void* d_ws, size_t ws_size,
                              hipStream_t stream) {
    const float* coords   = (const float*)d_in[0];
    const float* feats    = (const float*)d_in[1];
    const float* Ws1      = (const float*)d_in[2];
    const float* bs1      = (const float*)d_in[3];
    const float* Ws2      = (const float*)d_in[4];
    const float* bs2      = (const float*)d_in[5];
    const float* Wf1      = (const float*)d_in[6];
    const float* bf1      = (const float*)d_in[7];
    const float* Wf2      = (const float*)d_in[8];
    const float* bf2      = (const float*)d_in[9];
    const float* codebook = (const float*)d_in[10];

    float* out = (float*)d_out;            // [32768 tokens][25165824 quantized]
    float* out_tok = out;
    float* out_q   = out + M_ROWS;

    // ---- workspace layout (main path) ----
    const size_t SZ_COMB32 = (size_t)M_ROWS * DIM * 4;          // 100.66 MB
    const size_t SZ_COMB16 = (size_t)M_ROWS * DIM * 2;          //  50.33 MB
    const size_t SZ_CBB    = (size_t)VOCABN * DIM * 2;          //   6.29 MB
    const size_t SZ_CSQ    = (size_t)VOCABN * 4;
    const size_t SZ_LMIN   = (size_t)M_ROWS * NCB * 4;          //   4 MB
    const size_t SZ_LCI    = (size_t)M_ROWS * NCB * CAP2 * 4;   //  25 MB
    const size_t NEED = SZ_COMB32 + SZ_COMB16 + SZ_CBB + SZ_CSQ +
                        3 * SZ_LMIN + 2 * SZ_LCI;               // ~211 MB

    char* p = (char*)d_ws;
    float* comb32 = (float*)p;              p += SZ_COMB32;
    short* comb16 = (short*)p;              p += SZ_COMB16;
    __hip_bfloat16* cbb = (__hip_bfloat16*)p; p += SZ_CBB;
    float* csq = (float*)p;                 p += SZ_CSQ;

    if (ws_size >= NEED) {
        float* lmin_g = (float*)p;          p += SZ_LMIN;
        int*   lbidx_g = (int*)p;           p += SZ_LMIN;
        int*   lcnt_g = (int*)p;            p += SZ_LMIN;
        int*   lci_g = (int*)p;             p += SZ_LCI;
        float* lcd_g = (float*)p;           p += SZ_LCI;

        encode_kernel<<<M_ROWS / 32, 256, 0, stream>>>(
            coords, feats, Ws1, bs1, Ws2, bs2, Wf1, bf1, Wf2, bf2,
            comb32, comb16, 1);
        csq_cvt_kernel<<<VOCABN, 64, 0, stream>>>(codebook, csq, cbb);
        dim3 g1(NCB, M_ROWS / BM, 1);       // (32, 256)
        vq_phase1_kernel<<<g1, 256, 0, stream>>>(
            comb16, (const short*)cbb, csq, lmin_g, lbidx_g, lcnt_g, lci_g, lcd_g);
        vq_phase2_kernel<<<M_ROWS / 4, 256, 0, stream>>>(
            comb32, codebook, csq, lmin_g, lbidx_g, lcnt_g, lci_g, lcd_g,
            out_tok, out_q);
    } else {
        // R2 fallback (107 MB): comb32 + cbb + csq + toki
        int* toki = (int*)p;
        encode_kernel<<<M_ROWS / 32, 256, 0, stream>>>(
            coords, feats, Ws1, bs1, Ws2, bs2, Wf1, bf1, Wf2, bf2,
            comb32, comb16, 0);
        csq_cvt_kernel<<<VOCABN, 64, 0, stream>>>(codebook, csq, cbb);
        argmin_mfma_kernel<<<M_ROWS / QB, 256, 0, stream>>>(
            comb32, codebook, cbb, csq, out_tok, toki);
        gather_kernel<<<M_ROWS, 192, 0, stream>>>(toki, codebook, out_q);
    }
}

// Round 5
// 714.604 us; speedup vs baseline: 1.1567x; 1.1567x over previous
//
#include <hip/hip_runtime.h>
#include <hip/hip_bf16.h>
#include <cfloat>

// Problem constants (GeoTokenizer): B=8, N=4096 -> M=32768 rows
#define M_ROWS 32768
#define DIM    768
#define VOCABN 4096
#define HIDN   128
#define QB     64      // (fallback) queries per argmin block
#define CAP    32      // (fallback) candidate buffer per query
#define MARGIN 2.0f    // 2*delta; |approx-exact| bound delta=1.0 (validated R2-R4)

// Phase-1 GEMM tiling
#define BM 128
#define BN 128
#define NCB (VOCABN / BN)   // 32 code-blocks
#define CAP2 6              // stored candidates per (query, code-block)
#define NKC  (DIM / 32)     // 24 k-chunks of 32

typedef __attribute__((ext_vector_type(8))) short bf16x8;  // MFMA A/B frag
typedef __attribute__((ext_vector_type(4))) float f32x4;   // MFMA C/D frag

static __device__ __forceinline__ short f2b(float x) {
    __hip_bfloat16 h = __float2bfloat16(x);   // RNE
    return *reinterpret_cast<short*>(&h);
}

// Fragment-unit indexing (16 B units of 8 bf16):
//   A: unit = ((qt*8 + it)*NKC + kc)*64 + lane
//      holds comb[row = qt*128 + it*16 + (lane&15)][k = kc*32 + (lane>>4)*8 ..+8]
//   B: unit = ((cb*8 + jt)*NKC + kc)*64 + lane
//      holds codebook[code = cb*128 + jt*16 + (lane&15)][k = kc*32 + (lane>>4)*8 ..+8]

// ---------------------------------------------------------------------------
// Kernel 1: fused two-branch MLP encoder (fp32 exact). 32 rows/block.
// write16: emits comb16 in A-FRAGMENT order (scattered shorts, L2-combined).
// ---------------------------------------------------------------------------
__global__ __launch_bounds__(256) void encode_kernel(
    const float* __restrict__ coords, const float* __restrict__ feats,
    const float* __restrict__ Ws1, const float* __restrict__ bs1,
    const float* __restrict__ Ws2, const float* __restrict__ bs2,
    const float* __restrict__ Wf1, const float* __restrict__ bf1,
    const float* __restrict__ Wf2, const float* __restrict__ bf2,
    float* __restrict__ comb, short* __restrict__ comb16f, int write16)
{
    __shared__ float hs[32][HIDN];
    __shared__ float hf[32][HIDN];
    const int row0 = blockIdx.x * 32;
    const int t = threadIdx.x;

    #pragma unroll
    for (int k = 0; k < 16; ++k) {
        const int idx = t + k * 256;
        const int r = idx >> 7;
        const int j = idx & 127;
        const int row = row0 + r;
        const float c0 = coords[row * 2 + 0];
        const float c1 = coords[row * 2 + 1];
        float vs = fmaf(c0, Ws1[j], fmaf(c1, Ws1[HIDN + j], bs1[j]));
        hs[r][j] = fmaxf(vs, 0.0f);
        float vf = bf1[j];
        #pragma unroll
        for (int i = 0; i < 10; ++i)
            vf = fmaf(feats[row * 10 + i], Wf1[i * HIDN + j], vf);
        hf[r][j] = fmaxf(vf, 0.0f);
    }
    __syncthreads();

    float acc[3][32];
    #pragma unroll
    for (int dd = 0; dd < 3; ++dd) {
        const float base = bs2[t + dd * 256] + bf2[t + dd * 256];
        #pragma unroll
        for (int r = 0; r < 32; ++r) acc[dd][r] = base;
    }

    for (int jq = 0; jq < 32; ++jq) {
        float ws[3][4], wf[3][4];
        #pragma unroll
        for (int dd = 0; dd < 3; ++dd) {
            const int d = t + dd * 256;
            #pragma unroll
            for (int jj = 0; jj < 4; ++jj) {
                ws[dd][jj] = Ws2[(jq * 4 + jj) * DIM + d];
                wf[dd][jj] = Wf2[(jq * 4 + jj) * DIM + d];
            }
        }
        #pragma unroll
        for (int r = 0; r < 32; ++r) {
            const float4 h4s = *(const float4*)&hs[r][jq * 4];
            const float4 h4f = *(const float4*)&hf[r][jq * 4];
            #pragma unroll
            for (int dd = 0; dd < 3; ++dd) {
                float a = acc[dd][r];
                a = fmaf(h4s.x, ws[dd][0], a);
                a = fmaf(h4s.y, ws[dd][1], a);
                a = fmaf(h4s.z, ws[dd][2], a);
                a = fmaf(h4s.w, ws[dd][3], a);
                a = fmaf(h4f.x, wf[dd][0], a);
                a = fmaf(h4f.y, wf[dd][1], a);
                a = fmaf(h4f.z, wf[dd][2], a);
                a = fmaf(h4f.w, wf[dd][3], a);
                acc[dd][r] = a;
            }
        }
    }

    const int qt = row0 >> 7;   // 128-row group
    #pragma unroll
    for (int dd = 0; dd < 3; ++dd) {
        const int d = t + dd * 256;
        const int kc = d >> 5, kg = (d >> 3) & 3, jj = d & 7;
        #pragma unroll
        for (int r = 0; r < 32; ++r) {
            const int row = row0 + r;
            const float v = acc[dd][r];
            comb[(size_t)row * DIM + d] = v;
            if (write16) {
                const int it = (row >> 4) & 7, n = row & 15;
                const size_t unit = ((size_t)(qt * 8 + it) * NKC + kc) * 64 + kg * 16 + n;
                comb16f[unit * 8 + jj] = f2b(v);
            }
        }
    }
}

// ---------------------------------------------------------------------------
// Kernel 2: c_sq (fp32) + bf16 codebook conversion.
// swizzled=1 -> B-fragment order (main path); 0 -> row-major (fallback path).
// ---------------------------------------------------------------------------
__global__ __launch_bounds__(64) void csq_cvt_kernel(
    const float* __restrict__ codebook, float* __restrict__ csq,
    short* __restrict__ outb, int swizzled)
{
    const int v = blockIdx.x;
    const int l = threadIdx.x;
    float s = 0.0f;
    #pragma unroll
    for (int k = 0; k < DIM / 64; ++k) {
        const float x = codebook[(size_t)v * DIM + l + k * 64];
        if (!swizzled) outb[(size_t)v * DIM + l + k * 64] = f2b(x);
        s = fmaf(x, x, s);
    }
    #pragma unroll
    for (int off = 32; off >= 1; off >>= 1)
        s += __shfl_down(s, off);
    if (l == 0) csq[v] = s;

    if (swizzled) {
        const int cb = v >> 7, jt = (v >> 4) & 7, n = v & 15;
        for (int u = l; u < 96; u += 64) {      // 24 kc x 4 kg
            const int kc = u >> 2, kg = u & 3;
            const float* src = codebook + (size_t)v * DIM + kc * 32 + kg * 8;
            bf16x8 f;
            #pragma unroll
            for (int j = 0; j < 8; ++j) f[j] = f2b(src[j]);
            const size_t unit = ((size_t)(cb * 8 + jt) * NKC + kc) * 64 + kg * 16 + n;
            *(bf16x8*)(outb + unit * 8) = f;
        }
    }
}

// ---------------------------------------------------------------------------
// Kernel 3 (phase 1): barrier-free MFMA GEMM. Both operands pre-swizzled in
// fragment order; each wave global_load_dwordx4's its frags directly (no LDS
// tiles, no __syncthreads in the K-loop -> no vmcnt(0) convoy). Epilogue:
// per-(q,cb) min/argmin + margin candidates (R2-proven logic, lcd dropped).
// ---------------------------------------------------------------------------
__global__ __launch_bounds__(256) void vq_phase1_kernel(
    const short* __restrict__ comb16f, const short* __restrict__ cbf,
    const float* __restrict__ csq,
    float* __restrict__ lmin_g, int* __restrict__ lbidx_g,
    int* __restrict__ lcnt_g, int* __restrict__ lci_g)
{
    __shared__ float s_wmin[2][BM];
    __shared__ int   s_widx[2][BM];
    __shared__ float s_thr[BM];
    __shared__ int   s_cnt[BM];
    __shared__ int   s_ci[BM][CAP2];

    const int t = threadIdx.x;
    const int w = t >> 6, l = t & 63;
    const int lm = l & 15, quad = l >> 4;
    const int wr = w & 1, wc = w >> 1;
    const int cb = blockIdx.x;             // 0..31
    const int qt = blockIdx.y;             // 0..255
    const int q0 = qt * BM;

    if (t < BM) s_cnt[t] = 0;

    // fragment pointers (16B units; advance 64 units per kc)
    const short* ap[4];
    const short* bp[4];
    #pragma unroll
    for (int i = 0; i < 4; ++i) {
        ap[i] = comb16f + (((size_t)(qt * 8 + wr * 4 + i) * NKC) * 64 + l) * 8;
        bp[i] = cbf     + (((size_t)(cb * 8 + wc * 4 + i) * NKC) * 64 + l) * 8;
    }

    f32x4 acc[4][4];
    #pragma unroll
    for (int i = 0; i < 4; ++i)
        #pragma unroll
        for (int j = 0; j < 4; ++j) acc[i][j] = (f32x4){0.f, 0.f, 0.f, 0.f};

    // K loop: 24 chunks x (8 coalesced 1KB loads + 16 MFMA), no barriers.
    #pragma unroll 2
    for (int kc = 0; kc < NKC; ++kc) {
        bf16x8 a[4], b[4];
        #pragma unroll
        for (int i = 0; i < 4; ++i) a[i] = *(const bf16x8*)(ap[i] + kc * 512);
        #pragma unroll
        for (int j = 0; j < 4; ++j) b[j] = *(const bf16x8*)(bp[j] + kc * 512);
        #pragma unroll
        for (int i = 0; i < 4; ++i)
            #pragma unroll
            for (int j = 0; j < 4; ++j)
                acc[i][j] = __builtin_amdgcn_mfma_f32_16x16x32_bf16(
                    a[i], b[j], acc[i][j], 0, 0, 0);
    }

    // ---- epilogue: dist = csq - 2*dot (x_sq dropped, argmin-invariant)
    const int cbase = cb * BN + wc * 64;
    float cs[4];
    #pragma unroll
    for (int j = 0; j < 4; ++j) cs[j] = csq[cbase + j * 16 + lm];
    #pragma unroll
    for (int i = 0; i < 4; ++i)
        #pragma unroll
        for (int j = 0; j < 4; ++j)
            #pragma unroll
            for (int r = 0; r < 4; ++r)
                acc[i][j][r] = fmaf(-2.0f, acc[i][j][r], cs[j]);

    // per-query (i,r) min/argmin over j-tiles then over 16 lanes of the quad
    #pragma unroll
    for (int i = 0; i < 4; ++i)
        #pragma unroll
        for (int r = 0; r < 4; ++r) {
            float m = acc[i][0][r];
            int mi = cbase + 0 * 16 + lm;
            #pragma unroll
            for (int j = 1; j < 4; ++j) {
                const float d = acc[i][j][r];
                const int ci = cbase + j * 16 + lm;
                if (d < m || (d == m && ci < mi)) { m = d; mi = ci; }
            }
            #pragma unroll
            for (int off = 1; off <= 8; off <<= 1) {   // stays within quad
                const float om = __shfl_xor(m, off);
                const int oi = __shfl_xor(mi, off);
                if (om < m || (om == m && oi < mi)) { m = om; mi = oi; }
            }
            if (lm == 0) {
                const int qloc = wr * 64 + i * 16 + quad * 4 + r;
                s_wmin[wc][qloc] = m;
                s_widx[wc][qloc] = mi;
            }
        }
    __syncthreads();

    if (t < BM) {
        const float v0 = s_wmin[0][t], v1 = s_wmin[1][t];
        const int i0 = s_widx[0][t], i1 = s_widx[1][t];
        const float bm = fminf(v0, v1);
        const int bi = (v1 < v0 || (v1 == v0 && i1 < i0)) ? i1 : i0;
        const size_t base = (size_t)cb * M_ROWS + (q0 + t);   // [cb][q] coalesced
        lmin_g[base] = bm;
        lbidx_g[base] = bi;
        s_thr[t] = bm + MARGIN;
    }
    __syncthreads();

    // candidate pass: push everything within margin of the block-local min
    #pragma unroll
    for (int i = 0; i < 4; ++i)
        #pragma unroll
        for (int r = 0; r < 4; ++r) {
            const int qloc = wr * 64 + i * 16 + quad * 4 + r;
            const float thr = s_thr[qloc];
            #pragma unroll
            for (int j = 0; j < 4; ++j) {
                const float d = acc[i][j][r];
                if (d <= thr) {
                    const int p = atomicAdd(&s_cnt[qloc], 1);
                    if (p < CAP2) s_ci[qloc][p] = cbase + j * 16 + lm;
                }
            }
        }
    __syncthreads();

    if (t < BM) {
        const size_t base = (size_t)cb * M_ROWS + (q0 + t);
        int n = s_cnt[t];
        if (n > CAP2) n = CAP2;
        lcnt_g[base] = n;
        for (int p = 0; p < n; ++p)
            lci_g[base * CAP2 + p] = s_ci[t][p];
    }
}

// ---------------------------------------------------------------------------
// Kernel 4 (phase 2): G = min of 32 local mins; select cbs with lmin<=G+MARGIN
// (provable superset); exact fp32 re-rank of their anchors+candidates; fused
// gather. One wave per query; 4 queries per block.
// ---------------------------------------------------------------------------
#define P2CAP 48
__global__ __launch_bounds__(256) void vq_phase2_kernel(
    const float* __restrict__ comb32, const float* __restrict__ codebook,
    const float* __restrict__ csq,
    const float* __restrict__ lmin_g, const int* __restrict__ lbidx_g,
    const int* __restrict__ lcnt_g, const int* __restrict__ lci_g,
    float* __restrict__ out_tok_f, float* __restrict__ out_q)
{
    __shared__ int s2n[4];
    __shared__ int s2c[4][P2CAP];
    const int t = threadIdx.x, w = t >> 6, l = t & 63;
    const int q = blockIdx.x * 4 + w;
    if (l == 0) s2n[w] = 0;                 // wave-local; LDS ops in-order

    const size_t base = (size_t)l * M_ROWS + q;   // lane l = code-block l
    const float v = (l < NCB) ? lmin_g[base] : FLT_MAX;
    float g = v;
    #pragma unroll
    for (int off = 1; off <= 32; off <<= 1)
        g = fminf(g, __shfl_xor(g, off));
    const float thr = g + MARGIN;

    if (l < NCB && v <= thr) {
        int p = atomicAdd(&s2n[w], 1);
        if (p < P2CAP) s2c[w][p] = lbidx_g[base];   // anchor (cb-local argmin)
        int n = lcnt_g[base];
        if (n > CAP2) n = CAP2;
        for (int e = 0; e < n; ++e) {
            p = atomicAdd(&s2n[w], 1);
            if (p < P2CAP) s2c[w][p] = lci_g[base * CAP2 + e];
        }
    }
    __syncthreads();

    int ns = s2n[w];
    if (ns > P2CAP) ns = P2CAP;
    float bestd = FLT_MAX;
    int bestc = 0x7fffffff;
    const float4* xr = (const float4*)(comb32 + (size_t)q * DIM);
    for (int e = 0; e < ns; ++e) {
        const int c = s2c[w][e];
        const float4* cr = (const float4*)(codebook + (size_t)c * DIM);
        float dot = 0.0f;
        #pragma unroll
        for (int k = 0; k < 3; ++k) {
            const float4 x = xr[l + 64 * k];
            const float4 y = cr[l + 64 * k];
            dot = fmaf(x.x, y.x, fmaf(x.y, y.y, fmaf(x.z, y.z, fmaf(x.w, y.w, dot))));
        }
        #pragma unroll
        for (int off = 1; off <= 32; off <<= 1)
            dot += __shfl_xor(dot, off);     // bitwise-identical in all lanes
        const float d = fmaf(-2.0f, dot, csq[c]);
        if (d < bestd || (d == bestd && c < bestc)) { bestd = d; bestc = c; }
    }
    if (l == 0) out_tok_f[q] = (float)bestc;
    const float4* cr = (const float4*)(codebook + (size_t)bestc * DIM);
    float4* o4 = (float4*)(out_q + (size_t)q * DIM);
    #pragma unroll
    for (int k = 0; k < 3; ++k) o4[l + 64 * k] = cr[l + 64 * k];
}

// ===========================================================================
// FALLBACK PATH (R2, proven): used only if ws_size is too small.
// ===========================================================================
__global__ __launch_bounds__(256) void argmin_mfma_kernel(
    const float* __restrict__ comb, const float* __restrict__ codebook,
    const short* __restrict__ cbb, const float* __restrict__ csq,
    float* __restrict__ out_tok_f, int* __restrict__ tok_i)
{
    __shared__ int s_cnt[QB];
    __shared__ int s_cand[QB][CAP];

    const int t = threadIdx.x;
    const int w = t >> 6;
    const int l = t & 63;
    const int lm = l & 15;
    const int quad = l >> 4;
    const int q0 = blockIdx.x * QB;

    for (int i = t; i < QB; i += 256) s_cnt[i] = 0;
    __syncthreads();

    bf16x8 a_reg[24];
    {
        const int qa = q0 + w * 16 + lm;
        const float* ap = comb + (size_t)qa * DIM + quad * 8;
        #pragma unroll
        for (int kc = 0; kc < 24; ++kc) {
            const float4 lo = *(const float4*)(ap + kc * 32);
            const float4 hi = *(const float4*)(ap + kc * 32 + 4);
            bf16x8 f;
            f[0] = f2b(lo.x); f[1] = f2b(lo.y); f[2] = f2b(lo.z); f[3] = f2b(lo.w);
            f[4] = f2b(hi.x); f[5] = f2b(hi.y); f[6] = f2b(hi.z); f[7] = f2b(hi.w);
            a_reg[kc] = f;
        }
    }

    const short* bp = cbb + (size_t)lm * DIM + quad * 8;
    float runmin[4] = {FLT_MAX, FLT_MAX, FLT_MAX, FLT_MAX};

    for (int chunk = 0; chunk < VOCABN / 64; ++chunk) {
        const int c0 = chunk * 64;
        const short* bc = bp + (size_t)c0 * DIM;
        f32x4 acc[4];
        #pragma unroll
        for (int s = 0; s < 4; ++s) acc[s] = (f32x4){0.f, 0.f, 0.f, 0.f};

        #pragma unroll
        for (int kc = 0; kc < 24; ++kc) {
            const bf16x8 a = a_reg[kc];
            #pragma unroll
            for (int s = 0; s < 4; ++s) {
                const bf16x8 b = *(const bf16x8*)(bc + s * 16 * DIM + kc * 32);
                acc[s] = __builtin_amdgcn_mfma_f32_16x16x32_bf16(a, b, acc[s], 0, 0, 0);
            }
        }

        float d[4][4];
        float m[4] = {FLT_MAX, FLT_MAX, FLT_MAX, FLT_MAX};
        #pragma unroll
        for (int s = 0; s < 4; ++s) {
            const float csv = csq[c0 + s * 16 + lm];
            #pragma unroll
            for (int r = 0; r < 4; ++r) {
                d[s][r] = fmaf(-2.0f, acc[s][r], csv);
                m[r] = fminf(m[r], d[s][r]);
            }
        }
        #pragma unroll
        for (int r = 0; r < 4; ++r) {
            float vv = m[r];
            vv = fminf(vv, __shfl_xor(vv, 1));
            vv = fminf(vv, __shfl_xor(vv, 2));
            vv = fminf(vv, __shfl_xor(vv, 4));
            vv = fminf(vv, __shfl_xor(vv, 8));
            runmin[r] = fminf(runmin[r], vv);
        }
        #pragma unroll
        for (int s = 0; s < 4; ++s) {
            #pragma unroll
            for (int r = 0; r < 4; ++r) {
                if (d[s][r] <= runmin[r] + MARGIN) {
                    const int qloc = w * 16 + quad * 4 + r;
                    const int idx = atomicAdd(&s_cnt[qloc], 1);
                    if (idx < CAP) s_cand[qloc][idx] = c0 + s * 16 + lm;
                }
            }
        }
    }
    __syncthreads();

    const int qloc = t >> 2;
    const int sub = t & 3;
    const int qg = q0 + qloc;
    int n = s_cnt[qloc];
    if (n > CAP) n = CAP;
    float bestd = FLT_MAX;
    int bestc = 0x7fffffff;
    const float4* xr = (const float4*)(comb + (size_t)qg * DIM);
    for (int i = 0; i < n; ++i) {
        const int c = s_cand[qloc][i];
        const float4* cr = (const float4*)(codebook + (size_t)c * DIM);
        float dot = 0.0f;
        #pragma unroll 4
        for (int j = sub * 48; j < sub * 48 + 48; ++j) {
            const float4 x = xr[j];
            const float4 y = cr[j];
            dot = fmaf(x.x, y.x, fmaf(x.y, y.y, fmaf(x.z, y.z, fmaf(x.w, y.w, dot))));
        }
        dot += __shfl_xor(dot, 1);
        dot += __shfl_xor(dot, 2);
        const float dist = fmaf(-2.0f, dot, csq[c]);
        if (dist < bestd || (dist == bestd && c < bestc)) { bestd = dist; bestc = c; }
    }
    if (sub == 0) {
        out_tok_f[qg] = (float)bestc;
        tok_i[qg] = bestc;
    }
}

__global__ __launch_bounds__(192) void gather_kernel(
    const int* __restrict__ tok, const float* __restrict__ codebook,
    float* __restrict__ outq)
{
    const int row = blockIdx.x;
    const int t = threadIdx.x;
    const int token = tok[row];
    const float4* cb4 = (const float4*)(codebook + (size_t)token * DIM);
    float4* o4 = (float4*)(outq + (size_t)row * DIM);
    o4[t] = cb4[t];
}

// ===========================================================================
extern "C" void kernel_launch(void* const* d_in, const int* in_sizes, int n_in,
                              void* d_out, int out_size, void* d_ws, size_t ws_size,
                              hipStream_t stream) {
    const float* coords   = (const float*)d_in[0];
    const float* feats    = (const float*)d_in[1];
    const float* Ws1      = (const float*)d_in[2];
    const float* bs1      = (const float*)d_in[3];
    const float* Ws2      = (const float*)d_in[4];
    const float* bs2      = (const float*)d_in[5];
    const float* Wf1      = (const float*)d_in[6];
    const float* bf1      = (const float*)d_in[7];
    const float* Wf2      = (const float*)d_in[8];
    const float* bf2      = (const float*)d_in[9];
    const float* codebook = (const float*)d_in[10];

    float* out = (float*)d_out;            // [32768 tokens][25165824 quantized]
    float* out_tok = out;
    float* out_q   = out + M_ROWS;

    const size_t SZ_COMB32 = (size_t)M_ROWS * DIM * 4;          // 100.66 MB
    const size_t SZ_COMB16 = (size_t)M_ROWS * DIM * 2;          //  50.33 MB
    const size_t SZ_CBB    = (size_t)VOCABN * DIM * 2;          //   6.29 MB
    const size_t SZ_CSQ    = (size_t)VOCABN * 4;
    const size_t SZ_LMIN   = (size_t)M_ROWS * NCB * 4;          //   4 MB
    const size_t SZ_LCI    = (size_t)M_ROWS * NCB * CAP2 * 4;   //  25 MB
    const size_t NEED = SZ_COMB32 + SZ_COMB16 + SZ_CBB + SZ_CSQ +
                        3 * SZ_LMIN + SZ_LCI;                   // ~198 MB

    char* p = (char*)d_ws;
    float* comb32 = (float*)p;              p += SZ_COMB32;
    short* comb16f = (short*)p;             p += SZ_COMB16;   // fragment order
    short* cbx = (short*)p;                 p += SZ_CBB;      // frag (main) / row (fb)
    float* csq = (float*)p;                 p += SZ_CSQ;

    if (ws_size >= NEED) {
        float* lmin_g = (float*)p;          p += SZ_LMIN;
        int*   lbidx_g = (int*)p;           p += SZ_LMIN;
        int*   lcnt_g = (int*)p;            p += SZ_LMIN;
        int*   lci_g = (int*)p;             p += SZ_LCI;

        encode_kernel<<<M_ROWS / 32, 256, 0, stream>>>(
            coords, feats, Ws1, bs1, Ws2, bs2, Wf1, bf1, Wf2, bf2,
            comb32, comb16f, 1);
        csq_cvt_kernel<<<VOCABN, 64, 0, stream>>>(codebook, csq, cbx, 1);
        dim3 g1(NCB, M_ROWS / BM, 1);       // (32, 256)
        vq_phase1_kernel<<<g1, 256, 0, stream>>>(
            comb16f, cbx, csq, lmin_g, lbidx_g, lcnt_g, lci_g);
        vq_phase2_kernel<<<M_ROWS / 4, 256, 0, stream>>>(
            comb32, codebook, csq, lmin_g, lbidx_g, lcnt_g, lci_g,
            out_tok, out_q);
    } else {
        // R2 fallback: comb32 + cbb(row-major) + csq + toki
        int* toki = (int*)p;
        encode_kernel<<<M_ROWS / 32, 256, 0, stream>>>(
            coords, feats, Ws1, bs1, Ws2, bs2, Wf1, bf1, Wf2, bf2,
            comb32, comb16f, 0);
        csq_cvt_kernel<<<VOCABN, 64, 0, stream>>>(codebook, csq, cbx, 0);
        argmin_mfma_kernel<<<M_ROWS / QB, 256, 0, stream>>>(
            comb32, codebook, cbx, csq, out_tok, toki);
        gather_kernel<<<M_ROWS, 192, 0, stream>>>(toki, codebook, out_q);
    }
}